// Round 14
// baseline (319.329 us; speedup 1.0000x reference)
//
#include <hip/hip_runtime.h>
#include <hip/hip_bf16.h>

using bf16 = __bf16;
typedef __bf16 bf16x8 __attribute__((ext_vector_type(8)));
typedef float f32x4 __attribute__((ext_vector_type(4)));

__device__ __forceinline__ void gload16(const void* g, void* l) {
  __builtin_amdgcn_global_load_lds(
      (const __attribute__((address_space(1))) void*)g,
      (__attribute__((address_space(3))) void*)l, 16, 0, 0);
}

// software fp8 e4m3fn conversion, RNE, FTZ below 2^-6, clamp 448 (bias-free)
__device__ __forceinline__ unsigned char f32_e4m3(float f) {
  unsigned u = __float_as_uint(f);
  unsigned s = (u >> 24) & 0x80u;
  unsigned a = u & 0x7fffffffu;
  if (a < 0x3c800000u) return (unsigned char)s;            // FTZ
  if (a > 0x43e00000u) return (unsigned char)(s | 0x7eu);  // clamp 448
  unsigned r = a + 0x0007ffffu + ((a >> 20) & 1u);         // RNE at bit 20
  unsigned e = (r >> 23) - 120u;
  unsigned m = (r >> 20) & 7u;
  return (unsigned char)(s | (e << 3) | m);
}
__device__ __forceinline__ float e4m3_f32(unsigned char b) {  // positive only
  if (!(b & 0x78u)) return 0.f;
  return __uint_as_float(((((unsigned)(b >> 3) & 15u) + 120u) << 23) |
                         (((unsigned)b & 7u) << 20));
}

__device__ __forceinline__ void cvt8(const float* __restrict__ in,
                                     bf16* __restrict__ out, long i) {
  float4 f0 = *(const float4*)&in[i];
  float4 f1 = *(const float4*)&in[i + 4];
  bf16x8 o;
  o[0] = (bf16)f0.x; o[1] = (bf16)f0.y; o[2] = (bf16)f0.z; o[3] = (bf16)f0.w;
  o[4] = (bf16)f1.x; o[5] = (bf16)f1.y; o[6] = (bf16)f1.z; o[7] = (bf16)f1.w;
  *(bf16x8*)&out[i] = o;
}

__global__ __launch_bounds__(256) void cvt_f32_bf16(const float* __restrict__ in,
                                                    bf16* __restrict__ out, int n) {
  int i = (blockIdx.x * 256 + threadIdx.x) * 8;
  if (i < n) cvt8(in, out, i);
}

// ONE prep launch: cvt q/k/Wv, transpose-cvt Wq/Wk, zero GTf/rs
__global__ __launch_bounds__(256)
void prep(const float* __restrict__ q, bf16* __restrict__ qb,
          const float* __restrict__ k, bf16* __restrict__ kb,
          const float* __restrict__ wv, bf16* __restrict__ wvb,
          const float* __restrict__ Wq, bf16* __restrict__ WqTb,
          const float* __restrict__ Wk, bf16* __restrict__ WkTb,
          float* __restrict__ GTf, float* __restrict__ rs) {
  __shared__ float tile[64][65];
  const int b = blockIdx.x;
  const int t = threadIdx.x;
  if (b < 8192) { cvt8(q, qb, ((long)b * 256 + t) * 8); return; }
  if (b < 16384) { cvt8(k, kb, ((long)(b - 8192) * 256 + t) * 8); return; }
  if (b < 16896) { cvt8(wv, wvb, ((long)(b - 16384) * 256 + t) * 8); return; }
  if (b < 17408) {
    const int idx = b - 16896;
    const float* in = (idx & 1) ? Wk : Wq;
    bf16* out = (idx & 1) ? WkTb : WqTb;
    const int r0 = ((idx >> 1) & 15) * 64, c0 = (idx >> 5) * 64;
    const int r = t >> 4, c4 = (t & 15) * 4;
#pragma unroll
    for (int rr = 0; rr < 64; rr += 16) {
      float4 v = *(const float4*)&in[(long)(r0 + r + rr) * 1024 + c0 + c4];
      tile[r + rr][c4 + 0] = v.x; tile[r + rr][c4 + 1] = v.y;
      tile[r + rr][c4 + 2] = v.z; tile[r + rr][c4 + 3] = v.w;
    }
    __syncthreads();
    const int cc = t >> 2, rseg = (t & 3) * 16;
    bf16 tmp[16];
#pragma unroll
    for (int kk = 0; kk < 16; ++kk) tmp[kk] = (bf16)tile[rseg + kk][cc];
    *(bf16x8*)&out[(long)(c0 + cc) * 1024 + r0 + rseg] = *(bf16x8*)&tmp[0];
    *(bf16x8*)&out[(long)(c0 + cc) * 1024 + r0 + rseg + 8] = *(bf16x8*)&tmp[8];
    return;
  }
  const int zb = b - 17408;
  if (zb < 1024) *(float4*)&GTf[((long)zb * 256 + t) * 4] = make_float4(0, 0, 0, 0);
  else           *(float4*)&rs[((long)(zb - 1024) * 256 + t) * 4] = make_float4(0, 0, 0, 0);
}

// split-K GT GEMM: C += A @ B^T over K-slice [z*128, z*128+128). fp32 atomics.
__global__ __launch_bounds__(256)
void gemm_small_atomic(const bf16* __restrict__ A, const bf16* __restrict__ B,
                       float* __restrict__ C, int lda, int ldb, int ldc) {
  const int tid = threadIdx.x;
  const int wave = tid >> 6;
  const int lane = tid & 63;
  const int wr = wave >> 1, wc = wave & 1;
  const long brow = (long)blockIdx.x * 128;
  const long bcol = (long)blockIdx.y * 128;
  const int kofs = blockIdx.z * 128;

  __shared__ bf16 As[128 * 32];
  __shared__ bf16 Bs[128 * 32];
  f32x4 acc[4][4] = {};

  const int r0 = tid >> 2;
  const int c0 = (tid & 3) * 8;
  const bf16* ga = A + (brow + r0) * (long)lda + kofs + c0;
  const bf16* gb = B + (bcol + r0) * (long)ldb + kofs + c0;
  bf16* la0 = As + tid * 8;
  bf16* la1 = As + 2048 + tid * 8;
  bf16* lb0 = Bs + tid * 8;
  bf16* lb1 = Bs + 2048 + tid * 8;
  const int afo = (wr * 64 + (lane & 15)) * 32 + (lane >> 4) * 8;
  const int bfo = (wc * 64 + (lane & 15)) * 32 + (lane >> 4) * 8;

  for (int kt = 0; kt < 4; ++kt) {
    gload16(ga, la0);
    gload16(ga + (long)64 * lda, la1);
    gload16(gb, lb0);
    gload16(gb + (long)64 * ldb, lb1);
    ga += 32; gb += 32;
    __syncthreads();
    bf16x8 av[4], bv[4];
#pragma unroll
    for (int i = 0; i < 4; ++i) {
      av[i] = *(const bf16x8*)&As[afo + i * 512];
      bv[i] = *(const bf16x8*)&Bs[bfo + i * 512];
    }
#pragma unroll
    for (int mi = 0; mi < 4; ++mi)
#pragma unroll
      for (int ni = 0; ni < 4; ++ni)
        acc[mi][ni] = __builtin_amdgcn_mfma_f32_16x16x32_bf16(av[mi], bv[ni],
                                                              acc[mi][ni], 0, 0, 0);
    __syncthreads();
  }

  const int or0 = wr * 64 + ((lane >> 4) << 2);
  const int oc0 = wc * 64 + (lane & 15);
#pragma unroll
  for (int mi = 0; mi < 4; ++mi)
#pragma unroll
    for (int ni = 0; ni < 4; ++ni)
#pragma unroll
      for (int j = 0; j < 4; ++j)
        atomicAdd(&C[(brow + or0 + mi * 16 + j) * ldc + bcol + oc0 + ni * 16],
                  acc[mi][ni][j]);
}

// ---- bf16 256x256 core (r6/r9, best measured ~900 TF) ----
__device__ __forceinline__ void load_frags(const bf16* __restrict__ buf,
                                           int wr, int wc, int lk, int lr,
                                           bf16x8 (&R)[12]) {
#pragma unroll
  for (int mi = 0; mi < 8; ++mi) {
    const int r = wr * 128 + mi * 16 + lr;
    R[mi] = *(const bf16x8*)&buf[r * 32 + ((lk ^ ((r >> 1) & 3)) << 3)];
  }
#pragma unroll
  for (int ni = 0; ni < 4; ++ni) {
    const int r = wc * 64 + ni * 16 + lr;
    R[8 + ni] = *(const bf16x8*)&buf[8192 + r * 32 + ((lk ^ ((r >> 1) & 3)) << 3)];
  }
}

__device__ __forceinline__ void mfma_tile(const bf16x8 (&R)[12], f32x4 (&acc)[8][4]) {
  __builtin_amdgcn_s_setprio(1);
#pragma unroll
  for (int mi = 0; mi < 8; ++mi)
#pragma unroll
    for (int ni = 0; ni < 4; ++ni)
      acc[mi][ni] = __builtin_amdgcn_mfma_f32_16x16x32_bf16(R[mi], R[8 + ni], acc[mi][ni], 0, 0, 0);
  __builtin_amdgcn_s_setprio(0);
}

__device__ __forceinline__ void gemm_mainloop(const bf16* __restrict__ A,
                                              const bf16* __restrict__ B,
                                              int K, int lda, int ldb,
                                              long brow, long bcol,
                                              bf16 (*lds)[16384],
                                              f32x4 (&acc)[8][4]) {
  const int tid = threadIdx.x;
  const int lane = tid & 63;
  const int wave = tid >> 6;
  const int wr = wave >> 2, wc = wave & 3;
  const int srow = tid >> 2;
  const int scg  = (tid & 3) ^ ((srow >> 1) & 3);
  const bf16* gA = A + (brow + srow) * (long)lda + scg * 8;
  const bf16* gB = B + (bcol + srow) * (long)ldb + scg * 8;
  const long a128 = (long)lda << 7;
  const long b128 = (long)ldb << 7;
  const int nk = K >> 5;

  auto stage = [&](int t) {
    bf16* buf = (bf16*)lds[t & 3];
    const bf16* a = gA + (long)t * 32;
    const bf16* b = gB + (long)t * 32;
    gload16(a,        buf + tid * 8);
    gload16(a + a128, buf + 4096 + tid * 8);
    gload16(b,        buf + 8192 + tid * 8);
    gload16(b + b128, buf + 12288 + tid * 8);
  };

  const int lk = lane >> 4;
  const int lr = lane & 15;

  stage(0); stage(1); stage(2);
  asm volatile("s_waitcnt vmcnt(4)" ::: "memory");
  __builtin_amdgcn_s_barrier();

  bf16x8 R0[12], R1[12];
  load_frags((const bf16*)lds[0], wr, wc, lk, lr, R0);

  for (int t = 0; t < nk; t += 2) {
    load_frags((const bf16*)lds[(t + 1) & 3], wr, wc, lk, lr, R1);
    if (t + 3 < nk) stage(t + 3);
    mfma_tile(R0, acc);
    if (t + 3 < nk) { asm volatile("s_waitcnt vmcnt(4)" ::: "memory"); }
    else            { asm volatile("s_waitcnt vmcnt(0)" ::: "memory"); }
    __builtin_amdgcn_s_barrier();
    if (t + 2 < nk) load_frags((const bf16*)lds[(t + 2) & 3], wr, wc, lk, lr, R0);
    if (t + 4 < nk) stage(t + 4);
    mfma_tile(R1, acc);
    if (t + 4 < nk) { asm volatile("s_waitcnt vmcnt(4)" ::: "memory"); }
    else            { asm volatile("s_waitcnt vmcnt(0)" ::: "memory"); }
    __builtin_amdgcn_s_barrier();
  }
}

// scores: S8[b] = e4m3(exp(T1[b] @ qb[b]^T / 32)), rowsum of dequantized -> RS
__global__ __launch_bounds__(512, 2)
void gemm_scores(const bf16* __restrict__ T1, const bf16* __restrict__ qb,
                 unsigned char* __restrict__ S8, float* __restrict__ RS,
                 float scale) {
  int bx = blockIdx.x, by = blockIdx.y, bz = blockIdx.z;
  {
    const int gx = gridDim.x, gxy = gx * gridDim.y;
    const int nwg = gxy * gridDim.z;
    int lin = bx + gx * by + gxy * bz;
    lin = (lin & 7) * (nwg >> 3) + (lin >> 3);
    bz = lin / gxy; const int rem = lin - bz * gxy;
    by = rem / gx;  bx = rem - by * gx;
  }
  __shared__ bf16 lds[4][16384];
  f32x4 acc[8][4] = {};
  gemm_mainloop(T1 + (long)bz * 2097152, qb + (long)bz * 2097152,
                1024, 1024, 1024, (long)bx * 256, (long)by * 256, lds, acc);

  const int lane = threadIdx.x & 63;
  const int wave = threadIdx.x >> 6;
  const int wr = wave >> 2, wc = wave & 3;
  const long brow = (long)bx * 256, bcol = (long)by * 256;
  const int or0 = wr * 128 + ((lane >> 4) << 2);
  const int oc0 = wc * 64 + (lane & 15);
  unsigned char* S = S8 + (long)bz * 4194304;
#pragma unroll
  for (int mi = 0; mi < 8; ++mi) {
#pragma unroll
    for (int j = 0; j < 4; ++j) {
      const long row = brow + or0 + mi * 16 + j;
      float s = 0.f;
#pragma unroll
      for (int ni = 0; ni < 4; ++ni) {
        const unsigned char q = f32_e4m3(__expf(acc[mi][ni][j] * scale));
        S[row * 2048 + bcol + oc0 + ni * 16] = q;
        s += e4m3_f32(q);
      }
      s += __shfl_xor(s, 1, 64); s += __shfl_xor(s, 2, 64);
      s += __shfl_xor(s, 4, 64); s += __shfl_xor(s, 8, 64);
      if ((lane & 15) == 0) atomicAdd(&RS[(long)bz * 2048 + row], s);
    }
  }
}

// fused T1 (bf16 out) + Vpt (fp8 out)
__global__ __launch_bounds__(512, 2)
void gemm_fused_t1vpt(const bf16* __restrict__ kb, const bf16* __restrict__ GTb,
                      bf16* __restrict__ T1, const bf16* __restrict__ Wvb,
                      const bf16* __restrict__ qb, unsigned char* __restrict__ V8) {
  int id = blockIdx.x;
  id = (id & 7) * 64 + (id >> 3);
  const bf16 *A, *B; long brow, bcol; int isT1 = (id < 256); int bz = 0;
  if (isT1) {
    A = kb; B = GTb;
    brow = (long)(id & 63) * 256; bcol = (long)(id >> 6) * 256;
  } else {
    const int j = id - 256;
    bz = j >> 5;
    A = Wvb; B = qb + (long)bz * 2097152;
    brow = (long)(j & 3) * 256; bcol = (long)((j >> 2) & 7) * 256;
  }
  __shared__ bf16 lds[4][16384];
  f32x4 acc[8][4] = {};
  gemm_mainloop(A, B, 1024, 1024, 1024, brow, bcol, lds, acc);

  const int lane = threadIdx.x & 63;
  const int wave = threadIdx.x >> 6;
  const int wr = wave >> 2, wc = wave & 3;
  const int or0 = wr * 128 + ((lane >> 4) << 2);
  const int oc0 = wc * 64 + (lane & 15);
#pragma unroll
  for (int mi = 0; mi < 8; ++mi)
#pragma unroll
    for (int j = 0; j < 4; ++j) {
      const long row = brow + or0 + mi * 16 + j;
#pragma unroll
      for (int ni = 0; ni < 4; ++ni) {
        const long col = bcol + oc0 + ni * 16;
        if (isT1) T1[row * 1024 + col] = (bf16)acc[mi][ni][j];
        else      V8[(long)bz * 2097152 + row * 2048 + col] = f32_e4m3(acc[mi][ni][j]);
      }
    }
}

// PV in fp8: out[b] = (S8[b] @ V8[b]') * (1/RS[row]) + kb[b]
// 256x256 tile, BK=32 fp8 (32 B/row), 4-buf cyclic LDS 64 KB, 2 loads/tile,
// counted vmcnt(2), mfma_f32_16x16x32_fp8_fp8 (frag = 8 B/lane, k=(l>>4)*8+e).
__global__ __launch_bounds__(512, 2)
void gemm_pv8(const unsigned char* __restrict__ S8, const unsigned char* __restrict__ V8,
              float* __restrict__ out, const bf16* __restrict__ kb,
              const float* __restrict__ RS) {
  int bx = blockIdx.x, by = blockIdx.y, bz = blockIdx.z;
  {
    const int gx = gridDim.x, gxy = gx * gridDim.y;
    const int nwg = gxy * gridDim.z;
    int lin = bx + gx * by + gxy * bz;
    lin = (lin & 7) * (nwg >> 3) + (lin >> 3);
    bz = lin / gxy; const int rem = lin - bz * gxy;
    by = rem / gx;  bx = rem - by * gx;
  }
  const unsigned char* A = S8 + (long)bz * 4194304;   // 2048 x 2048 fp8
  const unsigned char* B = V8 + (long)bz * 2097152;   // 1024 x 2048 fp8
  const int tid = threadIdx.x;
  const int lane = tid & 63;
  const int wave = tid >> 6;
  const int wr = wave >> 2, wc = wave & 3;
  const long brow = (long)bx * 256, bcol = (long)by * 256;

  __shared__ unsigned char lds8[4][16384];   // 4 bufs x (A 8KB + B 8KB)
  f32x4 acc[8][4] = {};

  const int srow = tid >> 1;          // 0..255
  const int sc   = (tid & 1) * 16;
  const unsigned char* gA = A + (brow + srow) * 2048 + sc;
  const unsigned char* gB = B + (bcol + srow) * 2048 + sc;

  auto stage = [&](int t) {
    unsigned char* buf = lds8[t & 3];
    gload16(gA + (long)t * 32, buf + tid * 16);
    gload16(gB + (long)t * 32, buf + 8192 + tid * 16);
  };

  const int lk = lane >> 4;   // 0..3
  const int lr = lane & 15;

  auto loadf = [&](const unsigned char* buf, long (&R)[12]) {
#pragma unroll
    for (int mi = 0; mi < 8; ++mi)
      R[mi] = *(const long*)&buf[(wr * 128 + mi * 16 + lr) * 32 + lk * 8];
#pragma unroll
    for (int ni = 0; ni < 4; ++ni)
      R[8 + ni] = *(const long*)&buf[8192 + (wc * 64 + ni * 16 + lr) * 32 + lk * 8];
  };
  auto mf = [&](const long (&R)[12]) {
    __builtin_amdgcn_s_setprio(1);
#pragma unroll
    for (int mi = 0; mi < 8; ++mi)
#pragma unroll
      for (int ni = 0; ni < 4; ++ni)
        acc[mi][ni] = __builtin_amdgcn_mfma_f32_16x16x32_fp8_fp8(R[mi], R[8 + ni], acc[mi][ni], 0, 0, 0);
    __builtin_amdgcn_s_setprio(0);
  };

  const int nk = 64;   // K = 2048 fp8 / 32
  stage(0); stage(1); stage(2);
  asm volatile("s_waitcnt vmcnt(2)" ::: "memory");
  __builtin_amdgcn_s_barrier();

  long R0[12], R1[12];
  loadf(lds8[0], R0);

  for (int t = 0; t < nk; t += 2) {
    loadf(lds8[(t + 1) & 3], R1);
    if (t + 3 < nk) stage(t + 3);
    mf(R0);
    if (t + 3 < nk) { asm volatile("s_waitcnt vmcnt(2)" ::: "memory"); }
    else            { asm volatile("s_waitcnt vmcnt(0)" ::: "memory"); }
    __builtin_amdgcn_s_barrier();
    if (t + 2 < nk) loadf(lds8[(t + 2) & 3], R0);
    if (t + 4 < nk) stage(t + 4);
    mf(R1);
    if (t + 4 < nk) { asm volatile("s_waitcnt vmcnt(2)" ::: "memory"); }
    else            { asm volatile("s_waitcnt vmcnt(0)" ::: "memory"); }
    __builtin_amdgcn_s_barrier();
  }

  const int or0 = wr * 128 + ((lane >> 4) << 2);
  const int oc0 = wc * 64 + (lane & 15);
  float* C = out + (long)bz * 2097152;
  const bf16* Ad = kb + (long)bz * 2097152;
#pragma unroll
  for (int mi = 0; mi < 8; ++mi) {
#pragma unroll
    for (int j = 0; j < 4; ++j) {
      const long row = brow + or0 + mi * 16 + j;
      const float iv = 1.0f / RS[(long)bz * 2048 + row];
#pragma unroll
      for (int ni = 0; ni < 4; ++ni) {
        const long col = bcol + oc0 + ni * 16;
        C[row * 1024 + col] = acc[mi][ni][j] * iv + (float)Ad[row * 1024 + col];
      }
    }
  }
}

extern "C" void kernel_launch(void* const* d_in, const int* in_sizes, int n_in,
                              void* d_out, int out_size, void* d_ws, size_t ws_size,
                              hipStream_t stream) {
  const float* q_in = (const float*)d_in[0];  // (8,2048,1024)
  const float* k_in = (const float*)d_in[1];  // (8,2048,1024)
  const float* Wq   = (const float*)d_in[2];  // (1024,1024)
  const float* Wk   = (const float*)d_in[3];
  const float* Wv   = (const float*)d_in[4];
  float* out = (float*)d_out;
  char* ws = (char*)d_ws;

  bf16*  qb   = (bf16*)(ws);                        // 0   .. 32 MB
  bf16*  kb   = (bf16*)(ws + 33554432);             // 32  .. 64 MB
  unsigned char* S8 = (unsigned char*)(ws + 67108864);  // 64 .. 96 MB (fp8)
  float* GTf  = (float*)(ws + 100663296);           // 96 .. 100 MB
  bf16*  GTb  = (bf16*)(ws + 104857600);            // 100 .. 102 MB
  bf16*  T1   = (bf16*)(ws + 134217728);            // 128 .. 160 MB
  bf16*  Wvb  = (bf16*)(ws + 167772160);            // 2 MB
  bf16*  WqTb = (bf16*)(ws + 169869312);            // 2 MB
  bf16*  WkTb = (bf16*)(ws + 171966464);            // 2 MB
  float* rs   = (float*)(ws + 174063616);           // 64 KB
  unsigned char* V8 = (unsigned char*)(ws + 176160768); // 168 .. 184 MB (fp8)

  // 1) prep: conversions + weight transposes + zeros
  prep<<<18448, 256, 0, stream>>>(q_in, qb, k_in, kb, Wv, Wvb,
                                  Wq, WqTb, Wk, WkTb, GTf, rs);

  // 2) GT = Wq^T @ Wk (split-K z=8, fp32 atomics) -> bf16
  gemm_small_atomic<<<dim3(8, 8, 8), 256, 0, stream>>>(WqTb, WkTb, GTf, 1024, 1024, 1024);
  cvt_f32_bf16<<<512, 256, 0, stream>>>(GTf, GTb, 1048576);

  // 3) fused: T1 = kb @ GTb^T (bf16) ; V8[b] = fp8(Wvb @ qb[b]^T)
  gemm_fused_t1vpt<<<512, 512, 0, stream>>>(kb, GTb, T1, Wvb, qb, V8);

  // 4) S8[b] = fp8(exp(T1[b] @ qb[b]^T / 32)), rowsum(dequant) -> rs
  gemm_scores<<<dim3(8, 8, 8), 512, 0, stream>>>(T1, qb, S8, rs, 0.03125f);

  // 5) out[b] = (S8[b] @ V8[b]') / rs + kb[b]   (fp8 MFMA core)
  gemm_pv8<<<dim3(8, 4, 8), 512, 0, stream>>>(S8, V8, out, kb, rs);
}

// Round 15
// 282.192 us; speedup vs baseline: 1.1316x; 1.1316x over previous
//
#include <hip/hip_runtime.h>
#include <hip/hip_bf16.h>

using bf16 = __bf16;
typedef __bf16 bf16x8 __attribute__((ext_vector_type(8)));
typedef float f32x4 __attribute__((ext_vector_type(4)));

__device__ __forceinline__ void gload_lds16(const bf16* g, bf16* l) {
  __builtin_amdgcn_global_load_lds(
      (const __attribute__((address_space(1))) void*)g,
      (__attribute__((address_space(3))) void*)l, 16, 0, 0);
}

__device__ __forceinline__ void cvt8(const float* __restrict__ in,
                                     bf16* __restrict__ out, long i) {
  float4 f0 = *(const float4*)&in[i];
  float4 f1 = *(const float4*)&in[i + 4];
  bf16x8 o;
  o[0] = (bf16)f0.x; o[1] = (bf16)f0.y; o[2] = (bf16)f0.z; o[3] = (bf16)f0.w;
  o[4] = (bf16)f1.x; o[5] = (bf16)f1.y; o[6] = (bf16)f1.z; o[7] = (bf16)f1.w;
  *(bf16x8*)&out[i] = o;
}

// fp32 -> bf16, 8 elems/thread
__global__ __launch_bounds__(256) void cvt_f32_bf16(const float* __restrict__ in,
                                                    bf16* __restrict__ out, int n) {
  int i = (blockIdx.x * 256 + threadIdx.x) * 8;
  if (i < n) cvt8(in, out, i);
}

// ONE prep launch (all independent work):
//   blocks [0,8192):      qb  = bf16(q_in)
//   blocks [8192,16384):  kb  = bf16(k_in)
//   blocks [16384,16896): Wvb = bf16(Wv)
//   blocks [16896,17408): WqTb/WkTb = bf16(Wq^T / Wk^T)  (64x64 tiles)
//   blocks [17408,18448): zero GTf (1024 blks) + rs (16 blks)
__global__ __launch_bounds__(256)
void prep(const float* __restrict__ q, bf16* __restrict__ qb,
          const float* __restrict__ k, bf16* __restrict__ kb,
          const float* __restrict__ wv, bf16* __restrict__ wvb,
          const float* __restrict__ Wq, bf16* __restrict__ WqTb,
          const float* __restrict__ Wk, bf16* __restrict__ WkTb,
          float* __restrict__ GTf, float* __restrict__ rs) {
  __shared__ float tile[64][65];
  const int b = blockIdx.x;
  const int t = threadIdx.x;
  if (b < 8192) { cvt8(q, qb, ((long)b * 256 + t) * 8); return; }
  if (b < 16384) { cvt8(k, kb, ((long)(b - 8192) * 256 + t) * 8); return; }
  if (b < 16896) { cvt8(wv, wvb, ((long)(b - 16384) * 256 + t) * 8); return; }
  if (b < 17408) {
    const int idx = b - 16896;
    const float* in = (idx & 1) ? Wk : Wq;
    bf16* out = (idx & 1) ? WkTb : WqTb;
    const int r0 = ((idx >> 1) & 15) * 64, c0 = (idx >> 5) * 64;
    const int r = t >> 4, c4 = (t & 15) * 4;
#pragma unroll
    for (int rr = 0; rr < 64; rr += 16) {
      float4 v = *(const float4*)&in[(long)(r0 + r + rr) * 1024 + c0 + c4];
      tile[r + rr][c4 + 0] = v.x; tile[r + rr][c4 + 1] = v.y;
      tile[r + rr][c4 + 2] = v.z; tile[r + rr][c4 + 3] = v.w;
    }
    __syncthreads();
    const int cc = t >> 2, rseg = (t & 3) * 16;
    bf16 tmp[16];
#pragma unroll
    for (int kk = 0; kk < 16; ++kk) tmp[kk] = (bf16)tile[rseg + kk][cc];
    *(bf16x8*)&out[(long)(c0 + cc) * 1024 + r0 + rseg] = *(bf16x8*)&tmp[0];
    *(bf16x8*)&out[(long)(c0 + cc) * 1024 + r0 + rseg + 8] = *(bf16x8*)&tmp[8];
    return;
  }
  const int zb = b - 17408;
  if (zb < 1024) *(float4*)&GTf[((long)zb * 256 + t) * 4] = make_float4(0, 0, 0, 0);
  else           *(float4*)&rs[((long)(zb - 1024) * 256 + t) * 4] = make_float4(0, 0, 0, 0);
}

// small split-K GEMM: C += A @ B^T over K-slice [z*256, z*256+256).
__global__ __launch_bounds__(256)
void gemm_small_atomic(const bf16* __restrict__ A, const bf16* __restrict__ B,
                       float* __restrict__ C, int lda, int ldb, int ldc) {
  const int tid = threadIdx.x;
  const int wave = tid >> 6;
  const int lane = tid & 63;
  const int wr = wave >> 1, wc = wave & 1;
  const long brow = (long)blockIdx.x * 128;
  const long bcol = (long)blockIdx.y * 128;
  const int kofs = blockIdx.z * 256;

  __shared__ bf16 As[128 * 32];
  __shared__ bf16 Bs[128 * 32];
  f32x4 acc[4][4] = {};

  const int r0 = tid >> 2;
  const int c0 = (tid & 3) * 8;
  const bf16* ga = A + (brow + r0) * (long)lda + kofs + c0;
  const bf16* gb = B + (bcol + r0) * (long)ldb + kofs + c0;
  bf16* la0 = As + tid * 8;
  bf16* la1 = As + 2048 + tid * 8;
  bf16* lb0 = Bs + tid * 8;
  bf16* lb1 = Bs + 2048 + tid * 8;
  const int afo = (wr * 64 + (lane & 15)) * 32 + (lane >> 4) * 8;
  const int bfo = (wc * 64 + (lane & 15)) * 32 + (lane >> 4) * 8;

  for (int kt = 0; kt < 8; ++kt) {
    gload_lds16(ga, la0);
    gload_lds16(ga + (long)64 * lda, la1);
    gload_lds16(gb, lb0);
    gload_lds16(gb + (long)64 * ldb, lb1);
    ga += 32; gb += 32;
    __syncthreads();
    bf16x8 av[4], bv[4];
#pragma unroll
    for (int i = 0; i < 4; ++i) {
      av[i] = *(const bf16x8*)&As[afo + i * 512];
      bv[i] = *(const bf16x8*)&Bs[bfo + i * 512];
    }
#pragma unroll
    for (int mi = 0; mi < 4; ++mi)
#pragma unroll
      for (int ni = 0; ni < 4; ++ni)
        acc[mi][ni] = __builtin_amdgcn_mfma_f32_16x16x32_bf16(av[mi], bv[ni],
                                                              acc[mi][ni], 0, 0, 0);
    __syncthreads();
  }

  const int or0 = wr * 64 + ((lane >> 4) << 2);
  const int oc0 = wc * 64 + (lane & 15);
#pragma unroll
  for (int mi = 0; mi < 4; ++mi)
#pragma unroll
    for (int ni = 0; ni < 4; ++ni)
#pragma unroll
      for (int j = 0; j < 4; ++j)
        atomicAdd(&C[(brow + or0 + mi * 16 + j) * ldc + bcol + oc0 + ni * 16],
                  acc[mi][ni][j]);
}

// frags for one K-tile (BK=32): R[0..7]=A(mi), R[8..11]=B(ni). 12 x b128.
__device__ __forceinline__ void load_frags(const bf16* __restrict__ buf,
                                           int wr, int wc, int lk, int lr,
                                           bf16x8 (&R)[12]) {
#pragma unroll
  for (int mi = 0; mi < 8; ++mi) {
    const int r = wr * 128 + mi * 16 + lr;
    R[mi] = *(const bf16x8*)&buf[r * 32 + ((lk ^ ((r >> 1) & 3)) << 3)];
  }
#pragma unroll
  for (int ni = 0; ni < 4; ++ni) {
    const int r = wc * 64 + ni * 16 + lr;
    R[8 + ni] = *(const bf16x8*)&buf[8192 + r * 32 + ((lk ^ ((r >> 1) & 3)) << 3)];
  }
}

__device__ __forceinline__ void mfma_tile(const bf16x8 (&R)[12], f32x4 (&acc)[8][4]) {
  __builtin_amdgcn_s_setprio(1);
#pragma unroll
  for (int mi = 0; mi < 8; ++mi)
#pragma unroll
    for (int ni = 0; ni < 4; ++ni)
      acc[mi][ni] = __builtin_amdgcn_mfma_f32_16x16x32_bf16(R[mi], R[8 + ni], acc[mi][ni], 0, 0, 0);
  __builtin_amdgcn_s_setprio(0);
}

// r6/r9 main loop (best measured, ~900 TF): 256x256 tile, BK=32, 8 waves,
// 4-buffer cyclic LDS, reg double-buffer, counted vmcnt(4), 1 barrier/tile.
__device__ __forceinline__ void gemm_mainloop(const bf16* __restrict__ A,
                                              const bf16* __restrict__ B,
                                              int K, int lda, int ldb,
                                              long brow, long bcol,
                                              bf16 (*lds)[16384],
                                              f32x4 (&acc)[8][4]) {
  const int tid = threadIdx.x;
  const int lane = tid & 63;
  const int wave = tid >> 6;
  const int wr = wave >> 2, wc = wave & 3;
  const int srow = tid >> 2;
  const int scg  = (tid & 3) ^ ((srow >> 1) & 3);
  const bf16* gA = A + (brow + srow) * (long)lda + scg * 8;
  const bf16* gB = B + (bcol + srow) * (long)ldb + scg * 8;
  const long a128 = (long)lda << 7;
  const long b128 = (long)ldb << 7;
  const int nk = K >> 5;

  auto stage = [&](int t) {
    bf16* buf = (bf16*)lds[t & 3];
    const bf16* a = gA + (long)t * 32;
    const bf16* b = gB + (long)t * 32;
    gload_lds16(a,        buf + tid * 8);
    gload_lds16(a + a128, buf + 4096 + tid * 8);
    gload_lds16(b,        buf + 8192 + tid * 8);
    gload_lds16(b + b128, buf + 12288 + tid * 8);
  };

  const int lk = lane >> 4;
  const int lr = lane & 15;

  stage(0); stage(1); stage(2);
  asm volatile("s_waitcnt vmcnt(4)" ::: "memory");
  __builtin_amdgcn_s_barrier();

  bf16x8 R0[12], R1[12];
  load_frags((const bf16*)lds[0], wr, wc, lk, lr, R0);

  for (int t = 0; t < nk; t += 2) {
    load_frags((const bf16*)lds[(t + 1) & 3], wr, wc, lk, lr, R1);
    if (t + 3 < nk) stage(t + 3);
    mfma_tile(R0, acc);
    if (t + 3 < nk) { asm volatile("s_waitcnt vmcnt(4)" ::: "memory"); }
    else            { asm volatile("s_waitcnt vmcnt(0)" ::: "memory"); }
    __builtin_amdgcn_s_barrier();
    if (t + 2 < nk) load_frags((const bf16*)lds[(t + 2) & 3], wr, wc, lk, lr, R0);
    if (t + 4 < nk) stage(t + 4);
    mfma_tile(R1, acc);
    if (t + 4 < nk) { asm volatile("s_waitcnt vmcnt(4)" ::: "memory"); }
    else            { asm volatile("s_waitcnt vmcnt(0)" ::: "memory"); }
    __builtin_amdgcn_s_barrier();
  }
}

// EPI 1: bf16 C = exp(scale*acc), fused fp32 row-sums atomicAdd into RS.
// EPI 2: fp32 C = acc * (1/RS[row]) + (float)Add (Add bf16).
template <int EPI>
__global__ __launch_bounds__(512, 2)
void gemm_bt(const bf16* __restrict__ A, const bf16* __restrict__ B,
             void* __restrict__ Cv, const bf16* __restrict__ Add,
             float* __restrict__ RS,
             int K, int lda, int ldb, int ldc,
             long sA, long sB, long sC, long sAdd, float scale) {
  int bx = blockIdx.x, by = blockIdx.y, bz = blockIdx.z;
  {  // XCD chunked swizzle (nwg%8==0)
    const int gx = gridDim.x, gxy = gx * gridDim.y;
    const int nwg = gxy * gridDim.z;
    int lin = bx + gx * by + gxy * bz;
    lin = (lin & 7) * (nwg >> 3) + (lin >> 3);
    bz = lin / gxy; const int rem = lin - bz * gxy;
    by = rem / gx;  bx = rem - by * gx;
  }
  __shared__ bf16 lds[4][16384];
  f32x4 acc[8][4] = {};
  gemm_mainloop(A + (long)bz * sA, B + (long)bz * sB, K, lda, ldb,
                (long)bx * 256, (long)by * 256, lds, acc);

  const int lane = threadIdx.x & 63;
  const int wave = threadIdx.x >> 6;
  const int wr = wave >> 2, wc = wave & 3;
  const long brow = (long)bx * 256, bcol = (long)by * 256;
  const int or0 = wr * 128 + ((lane >> 4) << 2);
  const int oc0 = wc * 64 + (lane & 15);
#pragma unroll
  for (int mi = 0; mi < 8; ++mi) {
#pragma unroll
    for (int j = 0; j < 4; ++j) {
      const long row = brow + or0 + mi * 16 + j;
      if constexpr (EPI == 1) {
        bf16* C = (bf16*)Cv + (long)bz * sC;
        float s = 0.f;
#pragma unroll
        for (int ni = 0; ni < 4; ++ni) {
          const float e = __expf(acc[mi][ni][j] * scale);
          s += e;
          C[row * ldc + bcol + oc0 + ni * 16] = (bf16)e;
        }
        s += __shfl_xor(s, 1, 64); s += __shfl_xor(s, 2, 64);
        s += __shfl_xor(s, 4, 64); s += __shfl_xor(s, 8, 64);
        if ((lane & 15) == 0) atomicAdd(&RS[(long)bz * 2048 + row], s);
      } else {
        float* C = (float*)Cv + (long)bz * sC;
        const bf16* Ad = Add + (long)bz * sAdd;
        const float iv = 1.0f / RS[(long)bz * 2048 + row];
#pragma unroll
        for (int ni = 0; ni < 4; ++ni) {
          const long col = bcol + oc0 + ni * 16;
          C[row * ldc + col] = acc[mi][ni][j] * iv + (float)Ad[row * ldc + col];
        }
      }
    }
  }
}

// fused T1 + Vpt:
// blocks [0,256): T1 = kb @ GTb^T (M=16384,N=1024, 64x4 tiles, ldc 1024)
// blocks [256,512): Vpt[z] = Wvb @ qb[z]^T (M=1024,N=2048, 4x8 tiles x8 b, ldc 2048)
__global__ __launch_bounds__(512, 2)
void gemm_fused_t1vpt(const bf16* __restrict__ kb, const bf16* __restrict__ GTb,
                      bf16* __restrict__ T1, const bf16* __restrict__ Wvb,
                      const bf16* __restrict__ qb, bf16* __restrict__ Vpt) {
  int id = blockIdx.x;
  id = (id & 7) * 64 + (id >> 3);   // XCD chunked swizzle over 512
  const bf16 *A, *B; bf16* C; int ldc; long brow, bcol;
  if (id < 256) {
    A = kb; B = GTb; C = T1; ldc = 1024;
    brow = (long)(id & 63) * 256; bcol = (long)(id >> 6) * 256;
  } else {
    const int j = id - 256;
    const int bz = j >> 5;
    A = Wvb; B = qb + (long)bz * 2097152; C = Vpt + (long)bz * 2097152; ldc = 2048;
    brow = (long)(j & 3) * 256; bcol = (long)((j >> 2) & 7) * 256;
  }
  __shared__ bf16 lds[4][16384];
  f32x4 acc[8][4] = {};
  gemm_mainloop(A, B, 1024, 1024, 1024, brow, bcol, lds, acc);

  const int lane = threadIdx.x & 63;
  const int wave = threadIdx.x >> 6;
  const int wr = wave >> 2, wc = wave & 3;
  const int or0 = wr * 128 + ((lane >> 4) << 2);
  const int oc0 = wc * 64 + (lane & 15);
#pragma unroll
  for (int mi = 0; mi < 8; ++mi)
#pragma unroll
    for (int j = 0; j < 4; ++j) {
      const long row = brow + or0 + mi * 16 + j;
#pragma unroll
      for (int ni = 0; ni < 4; ++ni)
        C[row * ldc + bcol + oc0 + ni * 16] = (bf16)acc[mi][ni][j];
    }
}

extern "C" void kernel_launch(void* const* d_in, const int* in_sizes, int n_in,
                              void* d_out, int out_size, void* d_ws, size_t ws_size,
                              hipStream_t stream) {
  const float* q_in = (const float*)d_in[0];  // (8,2048,1024)
  const float* k_in = (const float*)d_in[1];  // (8,2048,1024)
  const float* Wq   = (const float*)d_in[2];  // (1024,1024)
  const float* Wk   = (const float*)d_in[3];
  const float* Wv   = (const float*)d_in[4];
  float* out = (float*)d_out;
  char* ws = (char*)d_ws;

  // layout (peak ~200 MB):
  bf16*  qb   = (bf16*)(ws);                  // 0   .. 32 MB
  bf16*  kb   = (bf16*)(ws + 33554432);       // 32  .. 64 MB
  bf16*  S    = (bf16*)(ws + 67108864);       // 64  .. 128 MB (after GT* dead)
  float* GTf  = (float*)(ws + 67108864);      // overlay S: 4 MB, dead pre-S
  bf16*  GTb  = (bf16*)(ws + 71303168);       // overlay S: 2 MB, dead pre-S
  bf16*  T1   = (bf16*)(ws + 134217728);      // 128 .. 160 MB
  bf16*  Wvb  = (bf16*)(ws + 167772160);      // 2 MB
  bf16*  WqTb = (bf16*)(ws + 169869312);      // 2 MB
  bf16*  WkTb = (bf16*)(ws + 171966464);      // 2 MB
  float* rs   = (float*)(ws + 174063616);     // 64 KB
  bf16*  Vpt  = (bf16*)(ws + 176160768);      // 168 .. 200 MB

  // 1) ONE prep launch: cvt q/k/Wv + transpose-cvt Wq/Wk + zero GTf/rs
  prep<<<18448, 256, 0, stream>>>(q_in, qb, k_in, kb, Wv, Wvb,
                                  Wq, WqTb, Wk, WkTb, GTf, rs);

  // 2) GT = Wq^T @ Wk  (fp32 atomic split-K) -> bf16
  gemm_small_atomic<<<dim3(8, 8, 4), 256, 0, stream>>>(WqTb, WkTb, GTf, 1024, 1024, 1024);
  cvt_f32_bf16<<<512, 256, 0, stream>>>(GTf, GTb, 1048576);

  // 3) fused: T1 = kb @ GTb^T ; Vpt[b] = Wvb @ qb[b]^T
  gemm_fused_t1vpt<<<512, 512, 0, stream>>>(kb, GTb, T1, Wvb, qb, Vpt);

  // 4) S[b] = exp(T1[b] @ qb[b]^T / 32), fused rowsum -> rs
  gemm_bt<1><<<dim3(8, 8, 8), 512, 0, stream>>>(
      T1, qb, S, nullptr, rs, 1024, 1024, 1024, 2048,
      2097152L, 2097152L, 4194304L, 0L, 0.03125f);

  // 5) out[b] = (S[b] @ Vpt[b]') / rs + kb[b]  (M=2048, N=1024, K=2048)
  gemm_bt<2><<<dim3(8, 4, 8), 512, 0, stream>>>(
      S, Vpt, out, kb, rs, 2048, 2048, 2048, 1024,
      4194304L, 2097152L, 2097152L, 2097152L, 1.0f);
}